// Round 2
// baseline (9456.721 us; speedup 1.0000x reference)
//
#include <hip/hip_runtime.h>

// LSTM persistent-kernel for MI355X (gfx950). B=64,T=512,D=512,U=1024.
// 256 cooperative blocks (1/CU), each owns 4 hidden units (16 gate cols).
// W slice (Wx;Wh = [1536 x 16]) pre-swizzled fp16 in LDS (48 KB).
// h broadcast via double-buffered fp16 global buffer.
// R2: grid barrier = per-block flag lines (NO atomic RMW; 256-way counter
// contention was ~12.5us/step in R1). Each thread polls one flag line.

#define TT 512
#define BB 64
#define DD 512
#define UUNITS 1024
#define G4 4096
#define NBLK 256
#define KTOT 1536
#define NKB_X 16
#define NKB_H 32
#define FLAG_STRIDE 32   // ints; 128 B per flag line

typedef _Float16 f16x8 __attribute__((ext_vector_type(8)));
typedef _Float16 f16x4 __attribute__((ext_vector_type(4)));
typedef float f32x4 __attribute__((ext_vector_type(4)));

__device__ __forceinline__ float sigmoidf_fast(float x) {
  return 1.0f / (1.0f + __expf(-x));
}
__device__ __forceinline__ float tanhf_fast(float x) {
  x = fminf(fmaxf(x, -15.0f), 15.0f);
  float e = __expf(2.0f * x);
  return (e - 1.0f) / (e + 1.0f);
}

__global__ void convert_inputs(const float* __restrict__ x,
                               const float* __restrict__ h0,
                               _Float16* __restrict__ x16,
                               _Float16* __restrict__ h16) {
  int i = blockIdx.x * blockDim.x + threadIdx.x;
  int stride = gridDim.x * blockDim.x;
  const int n4 = BB * TT * DD / 4;
  const float4* x4 = (const float4*)x;
  for (int idx = i; idx < n4; idx += stride) {
    float4 v = x4[idx];
    f16x4 o;
    o[0] = (_Float16)v.x; o[1] = (_Float16)v.y;
    o[2] = (_Float16)v.z; o[3] = (_Float16)v.w;
    *(f16x4*)(x16 + (size_t)idx * 4) = o;
  }
  if (i < BB * UUNITS) h16[i] = (_Float16)h0[i];
}

__global__ __launch_bounds__(256, 1) void lstm_persistent(
    const _Float16* __restrict__ x16,
    const float* __restrict__ c0,
    const float* __restrict__ Wx,
    const float* __restrict__ Wh,
    const float* __restrict__ b,
    _Float16* __restrict__ h_bufs,      // 2 x [B,U] fp16 ping-pong
    float* __restrict__ out,
    int* __restrict__ flags)            // NBLK lines, 128 B apart
{
  __shared__ _Float16 Blds[KTOT / 32 * 512];   // 48 KB
  __shared__ float gtile[4 * 256];

  const int wg   = blockIdx.x;
  const int tid  = threadIdx.x;
  const int wave = tid >> 6;
  const int lane = tid & 63;
  const int quad = lane >> 4;
  const int ncol = lane & 15;
  const int u0   = wg * 4;

  // ---- stage W slice into LDS (fp16, B-fragment swizzle) ----
  for (int i = 0; i < 24; ++i) {
    int idx = i * 256 + tid;
    int gate = idx & 3;
    int k = idx >> 2;
    const float* src = (k < DD) ? (Wx + (size_t)k * G4)
                                : (Wh + (size_t)(k - DD) * G4);
    float4 v = *(const float4*)(src + gate * 1024 + u0);
    int base = (k >> 5) * 512 + ((k >> 3) & 3) * 128 + (k & 7);
    Blds[base + (0 * 4 + gate) * 8] = (_Float16)v.x;
    Blds[base + (1 * 4 + gate) * 8] = (_Float16)v.y;
    Blds[base + (2 * 4 + gate) * 8] = (_Float16)v.z;
    Blds[base + (3 * 4 + gate) * 8] = (_Float16)v.w;
  }

  const int gcol = (ncol & 3) * 1024 + u0 + (ncol >> 2);
  const float bias = b[gcol];

  const int b_idx = wave * 16 + (lane >> 2);
  const int u_idx = u0 + (lane & 3);
  float c_st = c0[b_idx * UUNITS + u_idx];

  __syncthreads();

  const int arow = wave * 16 + ncol;
  const _Float16* xbase = x16 + ((size_t)arow * TT) * DD + quad * 8;
  float* gt = &gtile[wave * 256];
  int* my_flag_line = flags + tid * FLAG_STRIDE;   // thread tid polls block tid's flag

  for (int t = 0; t < TT; ++t) {
    f32x4 acc  = {bias, bias, bias, bias};
    f32x4 acc2 = {0.f, 0.f, 0.f, 0.f};

    // ---- x-part (no h dependence) : overlaps other blocks' arrival ----
    const _Float16* xrow = xbase + (size_t)t * DD;
#pragma unroll
    for (int kb = 0; kb < NKB_X; kb += 2) {
      f16x8 a0 = *(const f16x8*)(xrow + kb * 32);
      f16x8 b0 = *(const f16x8*)(&Blds[kb * 512 + quad * 128 + ncol * 8]);
      acc = __builtin_amdgcn_mfma_f32_16x16x32_f16(a0, b0, acc, 0, 0, 0);
      f16x8 a1 = *(const f16x8*)(xrow + (kb + 1) * 32);
      f16x8 b1 = *(const f16x8*)(&Blds[(kb + 1) * 512 + quad * 128 + ncol * 8]);
      acc2 = __builtin_amdgcn_mfma_f32_16x16x32_f16(a1, b1, acc2, 0, 0, 0);
    }

    // ---- barrier wait: h(t) visible when every flag >= t ----
    if (t > 0) {
      while (__hip_atomic_load(my_flag_line, __ATOMIC_RELAXED,
                               __HIP_MEMORY_SCOPE_AGENT) < t)
        __builtin_amdgcn_s_sleep(1);
      __builtin_amdgcn_fence(__ATOMIC_ACQUIRE, "agent");
      __syncthreads();
    }

    // ---- h-part : K = 512..1535 ----
    const _Float16* hrow =
        h_bufs + (size_t)(t & 1) * BB * UUNITS + (size_t)arow * UUNITS + quad * 8;
#pragma unroll
    for (int kb = 0; kb < NKB_H; kb += 2) {
      f16x8 a0 = *(const f16x8*)(hrow + kb * 32);
      f16x8 b0 = *(const f16x8*)(&Blds[(NKB_X + kb) * 512 + quad * 128 + ncol * 8]);
      acc = __builtin_amdgcn_mfma_f32_16x16x32_f16(a0, b0, acc, 0, 0, 0);
      f16x8 a1 = *(const f16x8*)(hrow + (kb + 1) * 32);
      f16x8 b1 = *(const f16x8*)(&Blds[(NKB_X + kb + 1) * 512 + quad * 128 + ncol * 8]);
      acc2 = __builtin_amdgcn_mfma_f32_16x16x32_f16(a1, b1, acc2, 0, 0, 0);
    }
    acc += acc2;

    // ---- epilogue ----
#pragma unroll
    for (int r = 0; r < 4; ++r)
      gt[(quad * 4 + r) * 16 + ncol] = acc[r];
    float4 g4v = *(const float4*)&gt[(lane >> 2) * 16 + (lane & 3) * 4];
    float ig = sigmoidf_fast(g4v.x);
    float fg = sigmoidf_fast(g4v.y);
    float gg = tanhf_fast(g4v.z);
    float og = sigmoidf_fast(g4v.w);
    float cn = fg * c_st + ig * gg;
    c_st = cn;
    float hn = og * tanhf_fast(cn);

    _Float16* hw = h_bufs + (size_t)((t + 1) & 1) * BB * UUNITS;
    hw[b_idx * UUNITS + u_idx] = (_Float16)hn;
    if (t == TT - 1) out[b_idx * UUNITS + u_idx] = hn;

    // ---- arrive: own flag line, plain release store (no RMW) ----
    if (t + 1 < TT) {
      __syncthreads();   // all waves' h stores issued
      if (tid == 0)
        __hip_atomic_store(flags + wg * FLAG_STRIDE, t + 1,
                           __ATOMIC_RELEASE, __HIP_MEMORY_SCOPE_AGENT);
    }
  }
}

extern "C" void kernel_launch(void* const* d_in, const int* in_sizes, int n_in,
                              void* d_out, int out_size, void* d_ws, size_t ws_size,
                              hipStream_t stream) {
  const float* x  = (const float*)d_in[0];
  const float* h0 = (const float*)d_in[1];
  const float* c0 = (const float*)d_in[2];
  const float* Wx = (const float*)d_in[3];
  const float* Wh = (const float*)d_in[4];
  const float* b  = (const float*)d_in[5];
  float* out = (float*)d_out;

  char* ws = (char*)d_ws;
  _Float16* x16  = (_Float16*)ws;                               // 32 MB
  _Float16* hbuf = (_Float16*)(ws + (size_t)BB * TT * DD * 2);  // 256 KB
  int* flags     = (int*)(ws + (size_t)BB * TT * DD * 2
                             + (size_t)2 * BB * UUNITS * 2);    // 32 KB

  hipMemsetAsync(flags, 0, NBLK * FLAG_STRIDE * sizeof(int), stream);
  hipLaunchKernelGGL(convert_inputs, dim3(1024), dim3(256), 0, stream,
                     x, h0, x16, hbuf);

  static void* args[8];
  args[0] = (void*)&x16;  args[1] = (void*)&c0;  args[2] = (void*)&Wx;
  args[3] = (void*)&Wh;   args[4] = (void*)&b;   args[5] = (void*)&hbuf;
  args[6] = (void*)&out;  args[7] = (void*)&flags;
  hipLaunchCooperativeKernel((void*)lstm_persistent, dim3(NBLK), dim3(256),
                             args, 0, stream);
}

// Round 3
// 5641.716 us; speedup vs baseline: 1.6762x; 1.6762x over previous
//
#include <hip/hip_runtime.h>

// LSTM persistent-kernel for MI355X (gfx950). B=64,T=512,D=512,U=1024.
// 256 cooperative blocks (1/CU), each owns 4 hidden units (16 gate cols).
// W slice (Wx;Wh = [1536 x 16]) pre-swizzled fp16 in LDS (48 KB).
// R3 barrier: two-phase centralized. Arrive = per-block flag line store
// (no RMW). Aggregate = block0/wave0 polls 256 flags (4/lane). Go = 8
// replicated lines, polled by ONE thread per block. Total in-flight poll
// loads ~500 vs R2's 65536 (LLC congestion was the R1/R2 bottleneck).
// h exchange: packed 8-B agent-scope bypass stores -> LLC; readers rely on
// thread0 acquire fence (buffer_inv) + plain vector loads (L2-cached).

#define TT 512
#define BB 64
#define DD 512
#define UUNITS 1024
#define G4 4096
#define NBLK 256
#define KTOT 1536
#define NKB_X 16
#define NKB_H 32
#define FLAG_STRIDE 32   // ints; 128 B per flag line
#define NGO 8            // replicated go lines

typedef _Float16 f16x8 __attribute__((ext_vector_type(8)));
typedef _Float16 f16x4 __attribute__((ext_vector_type(4)));
typedef float f32x4 __attribute__((ext_vector_type(4)));

__device__ __forceinline__ float sigmoidf_fast(float x) {
  return 1.0f / (1.0f + __expf(-x));
}
__device__ __forceinline__ float tanhf_fast(float x) {
  x = fminf(fmaxf(x, -15.0f), 15.0f);
  float e = __expf(2.0f * x);
  return (e - 1.0f) / (e + 1.0f);
}

__global__ void convert_inputs(const float* __restrict__ x,
                               const float* __restrict__ h0,
                               _Float16* __restrict__ x16,
                               _Float16* __restrict__ h16) {
  int i = blockIdx.x * blockDim.x + threadIdx.x;
  int stride = gridDim.x * blockDim.x;
  const int n4 = BB * TT * DD / 4;
  const float4* x4 = (const float4*)x;
  for (int idx = i; idx < n4; idx += stride) {
    float4 v = x4[idx];
    f16x4 o;
    o[0] = (_Float16)v.x; o[1] = (_Float16)v.y;
    o[2] = (_Float16)v.z; o[3] = (_Float16)v.w;
    *(f16x4*)(x16 + (size_t)idx * 4) = o;
  }
  if (i < BB * UUNITS) h16[i] = (_Float16)h0[i];
}

__global__ __launch_bounds__(256, 1) void lstm_persistent(
    const _Float16* __restrict__ x16,
    const float* __restrict__ c0,
    const float* __restrict__ Wx,
    const float* __restrict__ Wh,
    const float* __restrict__ b,
    _Float16* __restrict__ h_bufs,      // 2 x [B,U] fp16 ping-pong
    float* __restrict__ out,
    int* __restrict__ flags)            // NBLK flag lines + NGO go lines
{
  __shared__ _Float16 Blds[KTOT / 32 * 512];   // 48 KB
  __shared__ float gtile[4 * 256];

  const int wg   = blockIdx.x;
  const int tid  = threadIdx.x;
  const int wave = tid >> 6;
  const int lane = tid & 63;
  const int quad = lane >> 4;
  const int ncol = lane & 15;
  const int u0   = wg * 4;
  int* go = flags + NBLK * FLAG_STRIDE;

  // ---- stage W slice into LDS (fp16, B-fragment swizzle) ----
  for (int i = 0; i < 24; ++i) {
    int idx = i * 256 + tid;
    int gate = idx & 3;
    int k = idx >> 2;
    const float* src = (k < DD) ? (Wx + (size_t)k * G4)
                                : (Wh + (size_t)(k - DD) * G4);
    float4 v = *(const float4*)(src + gate * 1024 + u0);
    int base = (k >> 5) * 512 + ((k >> 3) & 3) * 128 + (k & 7);
    Blds[base + (0 * 4 + gate) * 8] = (_Float16)v.x;
    Blds[base + (1 * 4 + gate) * 8] = (_Float16)v.y;
    Blds[base + (2 * 4 + gate) * 8] = (_Float16)v.z;
    Blds[base + (3 * 4 + gate) * 8] = (_Float16)v.w;
  }

  const int gcol = (ncol & 3) * 1024 + u0 + (ncol >> 2);
  const float bias = b[gcol];

  const int b_idx = wave * 16 + (lane >> 2);
  const int u_idx = u0 + (lane & 3);
  float c_st = c0[b_idx * UUNITS + u_idx];

  __syncthreads();

  const int arow = wave * 16 + ncol;
  const _Float16* xbase = x16 + ((size_t)arow * TT) * DD + quad * 8;
  float* gt = &gtile[wave * 256];

  for (int t = 0; t < TT; ++t) {
    f32x4 acc  = {bias, bias, bias, bias};
    f32x4 acc2 = {0.f, 0.f, 0.f, 0.f};

    // ---- x-part (no h dependence) : overlaps barrier propagation ----
    const _Float16* xrow = xbase + (size_t)t * DD;
#pragma unroll
    for (int kb = 0; kb < NKB_X; kb += 2) {
      f16x8 a0 = *(const f16x8*)(xrow + kb * 32);
      f16x8 b0 = *(const f16x8*)(&Blds[kb * 512 + quad * 128 + ncol * 8]);
      acc = __builtin_amdgcn_mfma_f32_16x16x32_f16(a0, b0, acc, 0, 0, 0);
      f16x8 a1 = *(const f16x8*)(xrow + (kb + 1) * 32);
      f16x8 b1 = *(const f16x8*)(&Blds[(kb + 1) * 512 + quad * 128 + ncol * 8]);
      acc2 = __builtin_amdgcn_mfma_f32_16x16x32_f16(a1, b1, acc2, 0, 0, 0);
    }

    // ---- wait: ONE thread polls ONE go line; then invalidate caches ----
    if (t > 0) {
      if (tid == 0 && wg != 0) {
        int* gl = go + (wg & (NGO - 1)) * FLAG_STRIDE;
        while (__hip_atomic_load(gl, __ATOMIC_RELAXED,
                                 __HIP_MEMORY_SCOPE_AGENT) < t)
          __builtin_amdgcn_s_sleep(1);
      }
      if (tid == 0)
        __builtin_amdgcn_fence(__ATOMIC_ACQUIRE, "agent");
      __syncthreads();
    }

    // ---- h-part : K = 512..1535 ----
    const _Float16* hrow =
        h_bufs + (size_t)(t & 1) * BB * UUNITS + (size_t)arow * UUNITS + quad * 8;
#pragma unroll
    for (int kb = 0; kb < NKB_H; kb += 2) {
      f16x8 a0 = *(const f16x8*)(hrow + kb * 32);
      f16x8 b0 = *(const f16x8*)(&Blds[(NKB_X + kb) * 512 + quad * 128 + ncol * 8]);
      acc = __builtin_amdgcn_mfma_f32_16x16x32_f16(a0, b0, acc, 0, 0, 0);
      f16x8 a1 = *(const f16x8*)(hrow + (kb + 1) * 32);
      f16x8 b1 = *(const f16x8*)(&Blds[(NKB_X + kb + 1) * 512 + quad * 128 + ncol * 8]);
      acc2 = __builtin_amdgcn_mfma_f32_16x16x32_f16(a1, b1, acc2, 0, 0, 0);
    }
    acc += acc2;

    // ---- epilogue ----
#pragma unroll
    for (int r = 0; r < 4; ++r)
      gt[(quad * 4 + r) * 16 + ncol] = acc[r];
    float4 g4v = *(const float4*)&gt[(lane >> 2) * 16 + (lane & 3) * 4];
    float ig = sigmoidf_fast(g4v.x);
    float fg = sigmoidf_fast(g4v.y);
    float gg = tanhf_fast(g4v.z);
    float og = sigmoidf_fast(g4v.w);
    float cn = fg * c_st + ig * gg;
    c_st = cn;
    float hn = og * tanhf_fast(cn);

    if (t == TT - 1) {
      out[b_idx * UUNITS + u_idx] = hn;
    } else {
      // ---- pack 4 u-values per batch into one 8-B LLC-bypass store ----
      int src = (lane & 15) * 4;
      float v0 = __shfl(hn, src + 0);
      float v1 = __shfl(hn, src + 1);
      float v2 = __shfl(hn, src + 2);
      float v3 = __shfl(hn, src + 3);
      if (lane < 16) {
        union { f16x4 h; unsigned long long u; } cv;
        cv.h[0] = (_Float16)v0; cv.h[1] = (_Float16)v1;
        cv.h[2] = (_Float16)v2; cv.h[3] = (_Float16)v3;
        _Float16* dst = h_bufs + (size_t)((t + 1) & 1) * BB * UUNITS
                        + (size_t)(wave * 16 + lane) * UUNITS + u0;
        __hip_atomic_store((unsigned long long*)dst, cv.u,
                           __ATOMIC_RELAXED, __HIP_MEMORY_SCOPE_AGENT);
      }
      __syncthreads();   // emits s_waitcnt vmcnt(0): ALL waves' h stores drained
      if (tid == 0)
        __hip_atomic_store(flags + wg * FLAG_STRIDE, t + 1,
                           __ATOMIC_RELEASE, __HIP_MEMORY_SCOPE_AGENT);
      // ---- aggregator: block 0 wave 0 polls all flags, posts go ----
      if (wg == 0 && wave == 0) {
        int* f0 = flags + (lane * 4 + 0) * FLAG_STRIDE;
        int* f1 = flags + (lane * 4 + 1) * FLAG_STRIDE;
        int* f2 = flags + (lane * 4 + 2) * FLAG_STRIDE;
        int* f3 = flags + (lane * 4 + 3) * FLAG_STRIDE;
        for (;;) {
          int a0 = __hip_atomic_load(f0, __ATOMIC_RELAXED, __HIP_MEMORY_SCOPE_AGENT);
          int a1 = __hip_atomic_load(f1, __ATOMIC_RELAXED, __HIP_MEMORY_SCOPE_AGENT);
          int a2 = __hip_atomic_load(f2, __ATOMIC_RELAXED, __HIP_MEMORY_SCOPE_AGENT);
          int a3 = __hip_atomic_load(f3, __ATOMIC_RELAXED, __HIP_MEMORY_SCOPE_AGENT);
          int mn = min(min(a0, a1), min(a2, a3));
          if (__all(mn >= t + 1)) break;
        }
        __builtin_amdgcn_fence(__ATOMIC_ACQUIRE, "agent");
        if (lane < NGO)
          __hip_atomic_store(go + lane * FLAG_STRIDE, t + 1,
                             __ATOMIC_RELEASE, __HIP_MEMORY_SCOPE_AGENT);
      }
    }
  }
}

extern "C" void kernel_launch(void* const* d_in, const int* in_sizes, int n_in,
                              void* d_out, int out_size, void* d_ws, size_t ws_size,
                              hipStream_t stream) {
  const float* x  = (const float*)d_in[0];
  const float* h0 = (const float*)d_in[1];
  const float* c0 = (const float*)d_in[2];
  const float* Wx = (const float*)d_in[3];
  const float* Wh = (const float*)d_in[4];
  const float* b  = (const float*)d_in[5];
  float* out = (float*)d_out;

  char* ws = (char*)d_ws;
  _Float16* x16  = (_Float16*)ws;                               // 32 MB
  _Float16* hbuf = (_Float16*)(ws + (size_t)BB * TT * DD * 2);  // 256 KB
  int* flags     = (int*)(ws + (size_t)BB * TT * DD * 2
                             + (size_t)2 * BB * UUNITS * 2);    // flags+go

  hipMemsetAsync(flags, 0, (NBLK + NGO) * FLAG_STRIDE * sizeof(int), stream);
  hipLaunchKernelGGL(convert_inputs, dim3(1024), dim3(256), 0, stream,
                     x, h0, x16, hbuf);

  static void* args[8];
  args[0] = (void*)&x16;  args[1] = (void*)&c0;  args[2] = (void*)&Wx;
  args[3] = (void*)&Wh;   args[4] = (void*)&b;   args[5] = (void*)&hbuf;
  args[6] = (void*)&out;  args[7] = (void*)&flags;
  hipLaunchCooperativeKernel((void*)lstm_persistent, dim3(NBLK), dim3(256),
                             args, 0, stream);
}

// Round 4
// 4300.010 us; speedup vs baseline: 2.1992x; 1.3120x over previous
//
#include <hip/hip_runtime.h>

// LSTM persistent-kernel for MI355X (gfx950). B=64,T=512,D=512,U=1024.
// 256 cooperative blocks (1/CU), each owns 4 hidden units (16 gate cols).
// W slice (Wx;Wh = [1536 x 16]) pre-swizzled fp16 in LDS (48 KB).
// R4 barrier: arrive = atomic_fetch_add on 8 spread counter lines (32-way
// each); wait = wave0 polls the 8 counters directly (lane&7, tight loop).
// Removes R3's aggregator + go stage: 6 dependent fabric RTs -> 4.
// h exchange: packed 8-B agent-scope bypass stores; consumers use cached
// vector loads after a per-step acquire fence (L1/L2 inv).

#define TT 512
#define BB 64
#define DD 512
#define UUNITS 1024
#define G4 4096
#define NBLK 256
#define KTOT 1536
#define NKB_X 16
#define NKB_H 32
#define FLAG_STRIDE 32   // ints; 128 B per counter line
#define NCNT 8           // spread counter lines

typedef _Float16 f16x8 __attribute__((ext_vector_type(8)));
typedef _Float16 f16x4 __attribute__((ext_vector_type(4)));
typedef float f32x4 __attribute__((ext_vector_type(4)));

__device__ __forceinline__ float sigmoidf_fast(float x) {
  return 1.0f / (1.0f + __expf(-x));
}
__device__ __forceinline__ float tanhf_fast(float x) {
  x = fminf(fmaxf(x, -15.0f), 15.0f);
  float e = __expf(2.0f * x);
  return (e - 1.0f) / (e + 1.0f);
}

__global__ void convert_inputs(const float* __restrict__ x,
                               const float* __restrict__ h0,
                               _Float16* __restrict__ x16,
                               _Float16* __restrict__ h16) {
  int i = blockIdx.x * blockDim.x + threadIdx.x;
  int stride = gridDim.x * blockDim.x;
  const int n4 = BB * TT * DD / 4;
  const float4* x4 = (const float4*)x;
  for (int idx = i; idx < n4; idx += stride) {
    float4 v = x4[idx];
    f16x4 o;
    o[0] = (_Float16)v.x; o[1] = (_Float16)v.y;
    o[2] = (_Float16)v.z; o[3] = (_Float16)v.w;
    *(f16x4*)(x16 + (size_t)idx * 4) = o;
  }
  if (i < BB * UUNITS) h16[i] = (_Float16)h0[i];
}

__global__ __launch_bounds__(256, 1) void lstm_persistent(
    const _Float16* __restrict__ x16,
    const float* __restrict__ c0,
    const float* __restrict__ Wx,
    const float* __restrict__ Wh,
    const float* __restrict__ b,
    _Float16* __restrict__ h_bufs,      // 2 x [B,U] fp16 ping-pong
    float* __restrict__ out,
    int* __restrict__ counters)         // NCNT spread lines
{
  __shared__ _Float16 Blds[KTOT / 32 * 512];   // 48 KB
  __shared__ float gtile[4 * 256];

  const int wg   = blockIdx.x;
  const int tid  = threadIdx.x;
  const int wave = tid >> 6;
  const int lane = tid & 63;
  const int quad = lane >> 4;
  const int ncol = lane & 15;
  const int u0   = wg * 4;

  // ---- stage W slice into LDS (fp16, B-fragment swizzle) ----
  for (int i = 0; i < 24; ++i) {
    int idx = i * 256 + tid;
    int gate = idx & 3;
    int k = idx >> 2;
    const float* src = (k < DD) ? (Wx + (size_t)k * G4)
                                : (Wh + (size_t)(k - DD) * G4);
    float4 v = *(const float4*)(src + gate * 1024 + u0);
    int base = (k >> 5) * 512 + ((k >> 3) & 3) * 128 + (k & 7);
    Blds[base + (0 * 4 + gate) * 8] = (_Float16)v.x;
    Blds[base + (1 * 4 + gate) * 8] = (_Float16)v.y;
    Blds[base + (2 * 4 + gate) * 8] = (_Float16)v.z;
    Blds[base + (3 * 4 + gate) * 8] = (_Float16)v.w;
  }

  const int gcol = (ncol & 3) * 1024 + u0 + (ncol >> 2);
  const float bias = b[gcol];

  const int b_idx = wave * 16 + (lane >> 2);
  const int u_idx = u0 + (lane & 3);
  float c_st = c0[b_idx * UUNITS + u_idx];

  __syncthreads();

  const int arow = wave * 16 + ncol;
  const _Float16* xbase = x16 + ((size_t)arow * TT) * DD + quad * 8;
  float* gt = &gtile[wave * 256];
  int* my_cnt = counters + (lane & (NCNT - 1)) * FLAG_STRIDE;

  for (int t = 0; t < TT; ++t) {
    f32x4 acc  = {bias, bias, bias, bias};
    f32x4 acc2 = {0.f, 0.f, 0.f, 0.f};

    // ---- x-part (no h dependence) : overlaps barrier propagation ----
    const _Float16* xrow = xbase + (size_t)t * DD;
#pragma unroll
    for (int kb = 0; kb < NKB_X; kb += 2) {
      f16x8 a0 = *(const f16x8*)(xrow + kb * 32);
      f16x8 b0 = *(const f16x8*)(&Blds[kb * 512 + quad * 128 + ncol * 8]);
      acc = __builtin_amdgcn_mfma_f32_16x16x32_f16(a0, b0, acc, 0, 0, 0);
      f16x8 a1 = *(const f16x8*)(xrow + (kb + 1) * 32);
      f16x8 b1 = *(const f16x8*)(&Blds[(kb + 1) * 512 + quad * 128 + ncol * 8]);
      acc2 = __builtin_amdgcn_mfma_f32_16x16x32_f16(a1, b1, acc2, 0, 0, 0);
    }

    // ---- wait: wave0 polls the 8 counters (8 samplers per counter) ----
    if (t > 0) {
      if (wave == 0) {
        const int target = 32 * t;   // all 256 blocks finished step t-1
        while (!__all(__hip_atomic_load(my_cnt, __ATOMIC_RELAXED,
                                        __HIP_MEMORY_SCOPE_AGENT) >= target)) {
        }
      }
      if (tid == 0)
        __builtin_amdgcn_fence(__ATOMIC_ACQUIRE, "agent");  // L1/L2 inv
      __syncthreads();
    }

    // ---- h-part : K = 512..1535 (cached loads; fresh after inv) ----
    const _Float16* hrow =
        h_bufs + (size_t)(t & 1) * BB * UUNITS + (size_t)arow * UUNITS + quad * 8;
#pragma unroll
    for (int kb = 0; kb < NKB_H; kb += 2) {
      f16x8 a0 = *(const f16x8*)(hrow + kb * 32);
      f16x8 b0 = *(const f16x8*)(&Blds[(NKB_X + kb) * 512 + quad * 128 + ncol * 8]);
      acc = __builtin_amdgcn_mfma_f32_16x16x32_f16(a0, b0, acc, 0, 0, 0);
      f16x8 a1 = *(const f16x8*)(hrow + (kb + 1) * 32);
      f16x8 b1 = *(const f16x8*)(&Blds[(NKB_X + kb + 1) * 512 + quad * 128 + ncol * 8]);
      acc2 = __builtin_amdgcn_mfma_f32_16x16x32_f16(a1, b1, acc2, 0, 0, 0);
    }
    acc += acc2;

    // ---- epilogue ----
#pragma unroll
    for (int r = 0; r < 4; ++r)
      gt[(quad * 4 + r) * 16 + ncol] = acc[r];
    float4 g4v = *(const float4*)&gt[(lane >> 2) * 16 + (lane & 3) * 4];
    float ig = sigmoidf_fast(g4v.x);
    float fg = sigmoidf_fast(g4v.y);
    float gg = tanhf_fast(g4v.z);
    float og = sigmoidf_fast(g4v.w);
    float cn = fg * c_st + ig * gg;
    c_st = cn;
    float hn = og * tanhf_fast(cn);

    if (t == TT - 1) {
      out[b_idx * UUNITS + u_idx] = hn;
    } else {
      // ---- pack 4 u-values per batch into one 8-B LLC-bypass store ----
      int src = (lane & 15) * 4;
      float v0 = __shfl(hn, src + 0);
      float v1 = __shfl(hn, src + 1);
      float v2 = __shfl(hn, src + 2);
      float v3 = __shfl(hn, src + 3);
      if (lane < 16) {
        union { f16x4 h; unsigned long long u; } cv;
        cv.h[0] = (_Float16)v0; cv.h[1] = (_Float16)v1;
        cv.h[2] = (_Float16)v2; cv.h[3] = (_Float16)v3;
        _Float16* dst = h_bufs + (size_t)((t + 1) & 1) * BB * UUNITS
                        + (size_t)(wave * 16 + lane) * UUNITS + u0;
        __hip_atomic_store((unsigned long long*)dst, cv.u,
                           __ATOMIC_RELAXED, __HIP_MEMORY_SCOPE_AGENT);
      }
      __syncthreads();   // per-wave vmcnt(0): all h stores globally visible
      if (tid == 0)
        __hip_atomic_fetch_add(counters + (wg & (NCNT - 1)) * FLAG_STRIDE, 1,
                               __ATOMIC_RELAXED, __HIP_MEMORY_SCOPE_AGENT);
    }
  }
}

extern "C" void kernel_launch(void* const* d_in, const int* in_sizes, int n_in,
                              void* d_out, int out_size, void* d_ws, size_t ws_size,
                              hipStream_t stream) {
  const float* x  = (const float*)d_in[0];
  const float* h0 = (const float*)d_in[1];
  const float* c0 = (const float*)d_in[2];
  const float* Wx = (const float*)d_in[3];
  const float* Wh = (const float*)d_in[4];
  const float* b  = (const float*)d_in[5];
  float* out = (float*)d_out;

  char* ws = (char*)d_ws;
  _Float16* x16  = (_Float16*)ws;                               // 32 MB
  _Float16* hbuf = (_Float16*)(ws + (size_t)BB * TT * DD * 2);  // 256 KB
  int* counters  = (int*)(ws + (size_t)BB * TT * DD * 2
                             + (size_t)2 * BB * UUNITS * 2);

  hipMemsetAsync(counters, 0, NCNT * FLAG_STRIDE * sizeof(int), stream);
  hipLaunchKernelGGL(convert_inputs, dim3(1024), dim3(256), 0, stream,
                     x, h0, x16, hbuf);

  static void* args[8];
  args[0] = (void*)&x16;  args[1] = (void*)&c0;  args[2] = (void*)&Wx;
  args[3] = (void*)&Wh;   args[4] = (void*)&b;   args[5] = (void*)&hbuf;
  args[6] = (void*)&out;  args[7] = (void*)&counters;
  hipLaunchCooperativeKernel((void*)lstm_persistent, dim3(NBLK), dim3(256),
                             args, 0, stream);
}